// Round 1
// baseline (1248.412 us; speedup 1.0000x reference)
//
#include <hip/hip_runtime.h>
#include <hip/hip_bf16.h>

typedef short s16x8 __attribute__((ext_vector_type(8)));
typedef float f32x4 __attribute__((ext_vector_type(4)));
typedef unsigned short u16;

#define DMODEL 2048
#define NH     16
#define NKV    4
#define HD     128
#define NB     4
#define SS     2048
#define NTOK   8192   // NB*SS
#define NQKV   3072   // 2048 q + 512 k + 512 v

static __device__ __forceinline__ u16 f2bf(float f) {
  unsigned u = __builtin_bit_cast(unsigned, f);
  u += 0x7fffu + ((u >> 16) & 1u);          // RNE
  return (u16)(u >> 16);
}
static __device__ __forceinline__ float bf2f(u16 h) {
  unsigned u = ((unsigned)h) << 16;
  return __builtin_bit_cast(float, u);
}

typedef const __attribute__((address_space(1))) void* gas_p;
typedef __attribute__((address_space(3))) void* las_p;
#define GLOAD16(g, l) __builtin_amdgcn_global_load_lds((gas_p)(const void*)(g), (las_p)(void*)(l), 16, 0, 0)

// ---------------------------------------------------------------- cast: f32 -> bf16
// segments: x 16777216 | wq 4194304 | wk 1048576 | wv 1048576 | wo 4194304
__global__ void cast_all(const float* __restrict__ x,  const float* __restrict__ wq,
                         const float* __restrict__ wk, const float* __restrict__ wv,
                         const float* __restrict__ wo,
                         u16* __restrict__ xb, u16* __restrict__ wqkv, u16* __restrict__ wob)
{
  long gid = (long)blockIdx.x * 256 + threadIdx.x;
  long i = gid * 4;
  const float* src; u16* dst; long off;
  if (i < 16777216L)       { src = x;  dst = xb;             off = i; }
  else if (i < 20971520L)  { src = wq; dst = wqkv;           off = i - 16777216L; }
  else if (i < 22020096L)  { src = wk; dst = wqkv + 4194304; off = i - 20971520L; }
  else if (i < 23068672L)  { src = wv; dst = wqkv + 5242880; off = i - 22020096L; }
  else                     { src = wo; dst = wob;            off = i - 23068672L; }
  float4 v = *(const float4*)(src + off);
  ushort4 o;
  o.x = f2bf(v.x); o.y = f2bf(v.y); o.z = f2bf(v.z); o.w = f2bf(v.w);
  *(ushort4*)(dst + off) = o;
}

// ---------------------------------------------------------------- GEMM  C = A * B^T
// A: [M][K] bf16 row-major.  Bm: [N][K] bf16 row-major (weights, K contiguous).
// 128x128 tile, BK=32, 4 waves (2x2), each wave 64x64 = 4x4 frags of 16x16x32 MFMA.
// EPI 0: scatter into Qr[b,h,s,d], Kr[b,kvh,s,d], Vt[b,kvh,d,s] (bf16)
// EPI 1: f32 row-major [M][DMODEL] out
template<int NT, int EPI>
__global__ __launch_bounds__(256) void gemm_bt(
    const u16* __restrict__ A, const u16* __restrict__ Bm, int K,
    u16* __restrict__ Oq, u16* __restrict__ Ok, u16* __restrict__ Ov, float* __restrict__ Of)
{
  __shared__ __align__(16) u16 As[128 * 32];
  __shared__ __align__(16) u16 Bs[128 * 32];
  const int tid = threadIdx.x;
  const int bx = blockIdx.x % NT;         // col tile
  const int by = blockIdx.x / NT;         // row tile
  const int l = tid & 63, w = tid >> 6;
  const int wr = w >> 1, wc = w & 1;
  const int lg = l >> 4, lr = l & 15;
  const int rowBase = by * 128, colBase = bx * 128;

  f32x4 acc[4][4] = {};

  // staging map: thread t covers tile-linear bytes c*4096 + t*16
  const int arow = tid >> 2;              // tile row within 64-row half
  const int acol = (tid & 3) * 8;         // k element
  const u16* gA = A  + (long)(rowBase + arow) * K + acol;
  const u16* gB = Bm + (long)(colBase + arow) * K + acol;
  const long half = (long)64 * K;

  char* ldsA = (char*)As;
  char* ldsB = (char*)Bs;

  for (int k0 = 0; k0 < K; k0 += 32) {
    GLOAD16(gA + k0,        ldsA + w * 1024);
    GLOAD16(gA + half + k0, ldsA + 4096 + w * 1024);
    GLOAD16(gB + k0,        ldsB + w * 1024);
    GLOAD16(gB + half + k0, ldsB + 4096 + w * 1024);
    __syncthreads();

    s16x8 af[4], bfr[4];
#pragma unroll
    for (int m = 0; m < 4; m++) {
      int r = wr * 64 + m * 16 + lr;
      af[m] = *(const s16x8*)&As[r * 32 + lg * 8];
    }
#pragma unroll
    for (int n = 0; n < 4; n++) {
      int r = wc * 64 + n * 16 + lr;
      bfr[n] = *(const s16x8*)&Bs[r * 32 + lg * 8];
    }
#pragma unroll
    for (int m = 0; m < 4; m++)
#pragma unroll
      for (int n = 0; n < 4; n++)
        acc[m][n] = __builtin_amdgcn_mfma_f32_16x16x32_bf16(af[m], bfr[n], acc[m][n], 0, 0, 0);
    __syncthreads();
  }

#pragma unroll
  for (int m = 0; m < 4; m++)
#pragma unroll
    for (int n = 0; n < 4; n++)
#pragma unroll
      for (int r = 0; r < 4; r++) {
        int row = rowBase + wr * 64 + m * 16 + lg * 4 + r;   // token
        int col = colBase + wc * 64 + n * 16 + lr;
        float v = acc[m][n][r];
        if (EPI == 0) {
          int b = row >> 11, s = row & 2047;
          u16 hv = f2bf(v);
          if (col < 2048) {
            int hh = col >> 7, d = col & 127;
            Oq[(((long)(b * NH + hh)) * SS + s) * HD + d] = hv;
          } else if (col < 2560) {
            int c2 = col - 2048, kh = c2 >> 7, d = c2 & 127;
            Ok[(((long)(b * NKV + kh)) * SS + s) * HD + d] = hv;
          } else {
            int c2 = col - 2560, kh = c2 >> 7, d = c2 & 127;
            Ov[(((long)(b * NKV + kh)) * HD + d) * SS + s] = hv;   // V transposed [d][s]
          }
        } else {
          Of[(long)row * DMODEL + col] = v;
        }
      }
}

// ---------------------------------------------------------------- RoPE in-place on Qr, Kr
// rows = (NB*NH + NB*NKV) * SS = 163840; one thread per (row, pair i<64)
__global__ void rope_kernel(u16* __restrict__ Qr, u16* __restrict__ Kr)
{
  long gid = (long)blockIdx.x * 256 + threadIdx.x;
  int i = (int)(gid & 63);
  long row = gid >> 6;
  int s;
  u16* p;
  const long qrows = (long)NB * NH * SS;
  if (row < qrows) { s = (int)(row & 2047); p = Qr + row * HD; }
  else             { long r2 = row - qrows; s = (int)(r2 & 2047); p = Kr + r2 * HD; }
  float inv = exp2f(-(float)i * 0.20762050593046015f);   // log2(10000)/64
  float fr = (float)s * inv;
  float c = cosf(fr), sn = sinf(fr);
  float x1 = bf2f(p[i]), x2 = bf2f(p[i + 64]);
  p[i]      = f2bf(x1 * c + x2 * sn);
  p[i + 64] = f2bf(-x1 * sn + x2 * c);
}

// ---------------------------------------------------------------- flash attention (causal, GQA)
// grid (S/64, NH, NB); 4 waves/block, wave w owns q-rows [qt*64+w*16, +16), no barriers.
__global__ __launch_bounds__(256) void attn_fwd(const u16* __restrict__ Qr, const u16* __restrict__ Kr,
                                                const u16* __restrict__ Vt, u16* __restrict__ Y)
{
  __shared__ __align__(16) u16 Plds[4][16 * 72];   // per-wave P buffer, stride 72 kills conflicts
  const int tid = threadIdx.x, l = tid & 63, w = tid >> 6;
  const int lg = l >> 4, lr = l & 15;
  const int qt = blockIdx.x, h = blockIdx.y, b = blockIdx.z;
  const int kvh = h >> 2;                           // rep=4, consecutive repeat
  const int qRow = qt * 64 + w * 16;
  const u16* Qh = Qr + (((long)(b * NH + h)) * SS + qRow) * HD;
  const u16* Kh = Kr + ((long)(b * NKV + kvh)) * SS * HD;
  const u16* Vh = Vt + ((long)(b * NKV + kvh)) * HD * SS;
  u16* Yh = Y + ((long)b * SS) * DMODEL + h * HD;

  s16x8 qf[4];
#pragma unroll
  for (int kk = 0; kk < 4; kk++)
    qf[kk] = *(const s16x8*)(Qh + (long)lr * HD + kk * 32 + lg * 8);

  float mrun[4] = {-1e30f, -1e30f, -1e30f, -1e30f};
  float lrun[4] = {0.f, 0.f, 0.f, 0.f};
  f32x4 oacc[8] = {};
  const float scale = 0.08838834764831845f;         // 1/sqrt(128)
  u16* myP = &Plds[w][0];
  const int kvEnd = qRow + 16;

  for (int kvb = 0; kvb < kvEnd; kvb += 64) {
    // ---- S = Q K^T  (16 q x 64 kv)
    f32x4 sacc[4] = {};
#pragma unroll
    for (int kk = 0; kk < 4; kk++) {
#pragma unroll
      for (int n = 0; n < 4; n++) {
        s16x8 kf = *(const s16x8*)(Kh + ((long)(kvb + n * 16 + lr)) * HD + kk * 32 + lg * 8);
        sacc[n] = __builtin_amdgcn_mfma_f32_16x16x32_bf16(qf[kk], kf, sacc[n], 0, 0, 0);
      }
    }
    // ---- scale + causal mask + row max
    float mx[4] = {-1e30f, -1e30f, -1e30f, -1e30f};
#pragma unroll
    for (int n = 0; n < 4; n++) {
      int col = kvb + n * 16 + lr;
#pragma unroll
      for (int r = 0; r < 4; r++) {
        int row = qRow + lg * 4 + r;
        float v = (col <= row) ? sacc[n][r] * scale : -1e30f;
        sacc[n][r] = v;
        mx[r] = fmaxf(mx[r], v);
      }
    }
#pragma unroll
    for (int r = 0; r < 4; r++) {
      mx[r] = fmaxf(mx[r], __shfl_xor(mx[r], 1));
      mx[r] = fmaxf(mx[r], __shfl_xor(mx[r], 2));
      mx[r] = fmaxf(mx[r], __shfl_xor(mx[r], 4));
      mx[r] = fmaxf(mx[r], __shfl_xor(mx[r], 8));
    }
    float sf[4], rs[4] = {0.f, 0.f, 0.f, 0.f};
#pragma unroll
    for (int r = 0; r < 4; r++) {
      float mnew = fmaxf(mrun[r], mx[r]);
      sf[r] = __expf(mrun[r] - mnew);
      mrun[r] = mnew;
    }
    // ---- P = exp(S - m); write P^T staging + row sums
#pragma unroll
    for (int n = 0; n < 4; n++)
#pragma unroll
      for (int r = 0; r < 4; r++) {
        float p = __expf(sacc[n][r] - mrun[r]);
        rs[r] += p;
        myP[(lg * 4 + r) * 72 + n * 16 + lr] = f2bf(p);
      }
#pragma unroll
    for (int r = 0; r < 4; r++) {
      rs[r] += __shfl_xor(rs[r], 1);
      rs[r] += __shfl_xor(rs[r], 2);
      rs[r] += __shfl_xor(rs[r], 4);
      rs[r] += __shfl_xor(rs[r], 8);
      lrun[r] = lrun[r] * sf[r] + rs[r];
    }
#pragma unroll
    for (int n = 0; n < 8; n++)
#pragma unroll
      for (int r = 0; r < 4; r++) oacc[n][r] *= sf[r];

    asm volatile("s_waitcnt lgkmcnt(0)" ::: "memory");   // drain P writes (cross-lane, same wave)
    s16x8 pa[2];
    pa[0] = *(const s16x8*)(myP + lr * 72 + lg * 8);
    pa[1] = *(const s16x8*)(myP + lr * 72 + 32 + lg * 8);
    // ---- O += P V   (V stored transposed: Vh[d][s])
#pragma unroll
    for (int kk = 0; kk < 2; kk++)
#pragma unroll
      for (int n = 0; n < 8; n++) {
        s16x8 vf = *(const s16x8*)(Vh + ((long)(n * 16 + lr)) * SS + kvb + kk * 32 + lg * 8);
        oacc[n] = __builtin_amdgcn_mfma_f32_16x16x32_bf16(pa[kk], vf, oacc[n], 0, 0, 0);
      }
  }

#pragma unroll
  for (int r = 0; r < 4; r++) lrun[r] = 1.f / lrun[r];
#pragma unroll
  for (int n = 0; n < 8; n++)
#pragma unroll
    for (int r = 0; r < 4; r++) {
      float v = oacc[n][r] * lrun[r];
      Yh[(long)(qRow + lg * 4 + r) * DMODEL + n * 16 + lr] = f2bf(v);
    }
}

// ---------------------------------------------------------------- launch
extern "C" void kernel_launch(void* const* d_in, const int* in_sizes, int n_in,
                              void* d_out, int out_size, void* d_ws, size_t ws_size,
                              hipStream_t stream) {
  const float* x  = (const float*)d_in[0];
  const float* wq = (const float*)d_in[1];
  const float* wk = (const float*)d_in[2];
  const float* wv = (const float*)d_in[3];
  const float* wo = (const float*)d_in[4];
  float* out = (float*)d_out;
  char* ws = (char*)d_ws;

  u16* Xb   = (u16*)ws;                    // 33,554,432 B  (aliased as Y after qkv gemm)
  u16* Wqkv = (u16*)(ws + 33554432);       // 12,582,912 B
  u16* Wob  = (u16*)(ws + 46137344);       //  8,388,608 B
  u16* Qr   = (u16*)(ws + 54525952);       // 33,554,432 B
  u16* Kr   = (u16*)(ws + 88080384);       //  8,388,608 B
  u16* Vt   = (u16*)(ws + 96468992);       //  8,388,608 B  (total 104,857,600 B)
  u16* Y    = Xb;                          // x no longer needed after qkv gemm

  cast_all<<<26624, 256, 0, stream>>>(x, wq, wk, wv, wo, Xb, Wqkv, Wob);
  gemm_bt<24, 0><<<1536, 256, 0, stream>>>(Xb, Wqkv, DMODEL, Qr, Kr, Vt, nullptr);
  rope_kernel<<<40960, 256, 0, stream>>>(Qr, Kr);
  dim3 ag(SS / 64, NH, NB);
  attn_fwd<<<ag, 256, 0, stream>>>(Qr, Kr, Vt, Y);
  gemm_bt<16, 1><<<1024, 256, 0, stream>>>(Y, Wob, DMODEL, nullptr, nullptr, nullptr, out);
}

// Round 2
// 570.597 us; speedup vs baseline: 2.1879x; 2.1879x over previous
//
#include <hip/hip_runtime.h>
#include <hip/hip_bf16.h>

typedef short s16x8 __attribute__((ext_vector_type(8)));
typedef float f32x4 __attribute__((ext_vector_type(4)));
typedef unsigned short u16;

#define DMODEL 2048
#define NH     16
#define NKV    4
#define HD     128
#define NB     4
#define SS     2048

static __device__ __forceinline__ u16 f2bf(float f) {
  unsigned u = __builtin_bit_cast(unsigned, f);
  u += 0x7fffu + ((u >> 16) & 1u);          // RNE
  return (u16)(u >> 16);
}
static __device__ __forceinline__ float bf2f(u16 h) {
  unsigned u = ((unsigned)h) << 16;
  return __builtin_bit_cast(float, u);
}

typedef const __attribute__((address_space(1))) void* gas_p;
typedef __attribute__((address_space(3))) void* las_p;
#define GLOAD16(g, l) __builtin_amdgcn_global_load_lds((gas_p)(const void*)(g), (las_p)(void*)(l), 16, 0, 0)

// ---------------------------------------------------------------- cast: f32 -> bf16
__global__ void cast_all(const float* __restrict__ x,  const float* __restrict__ wq,
                         const float* __restrict__ wk, const float* __restrict__ wv,
                         const float* __restrict__ wo,
                         u16* __restrict__ xb, u16* __restrict__ wqkv, u16* __restrict__ wob)
{
  long gid = (long)blockIdx.x * 256 + threadIdx.x;
  long i = gid * 4;
  const float* src; u16* dst; long off;
  if (i < 16777216L)       { src = x;  dst = xb;             off = i; }
  else if (i < 20971520L)  { src = wq; dst = wqkv;           off = i - 16777216L; }
  else if (i < 22020096L)  { src = wk; dst = wqkv + 4194304; off = i - 20971520L; }
  else if (i < 23068672L)  { src = wv; dst = wqkv + 5242880; off = i - 22020096L; }
  else                     { src = wo; dst = wob;            off = i - 23068672L; }
  float4 v = *(const float4*)(src + off);
  ushort4 o;
  o.x = f2bf(v.x); o.y = f2bf(v.y); o.z = f2bf(v.z); o.w = f2bf(v.w);
  *(ushort4*)(dst + off) = o;
}

// ---------------------------------------------------------------- GEMM  C = A * B^T (unchanged from R1)
template<int NT, int EPI>
__global__ __launch_bounds__(256) void gemm_bt(
    const u16* __restrict__ A, const u16* __restrict__ Bm, int K,
    u16* __restrict__ Oq, u16* __restrict__ Ok, u16* __restrict__ Ov, float* __restrict__ Of)
{
  __shared__ __align__(16) u16 As[128 * 32];
  __shared__ __align__(16) u16 Bs[128 * 32];
  const int tid = threadIdx.x;
  const int bx = blockIdx.x % NT;
  const int by = blockIdx.x / NT;
  const int l = tid & 63, w = tid >> 6;
  const int wr = w >> 1, wc = w & 1;
  const int lg = l >> 4, lr = l & 15;
  const int rowBase = by * 128, colBase = bx * 128;

  f32x4 acc[4][4] = {};

  const int arow = tid >> 2;
  const int acol = (tid & 3) * 8;
  const u16* gA = A  + (long)(rowBase + arow) * K + acol;
  const u16* gB = Bm + (long)(colBase + arow) * K + acol;
  const long half = (long)64 * K;

  char* ldsA = (char*)As;
  char* ldsB = (char*)Bs;

  for (int k0 = 0; k0 < K; k0 += 32) {
    GLOAD16(gA + k0,        ldsA + w * 1024);
    GLOAD16(gA + half + k0, ldsA + 4096 + w * 1024);
    GLOAD16(gB + k0,        ldsB + w * 1024);
    GLOAD16(gB + half + k0, ldsB + 4096 + w * 1024);
    __syncthreads();

    s16x8 af[4], bfr[4];
#pragma unroll
    for (int m = 0; m < 4; m++) {
      int r = wr * 64 + m * 16 + lr;
      af[m] = *(const s16x8*)&As[r * 32 + lg * 8];
    }
#pragma unroll
    for (int n = 0; n < 4; n++) {
      int r = wc * 64 + n * 16 + lr;
      bfr[n] = *(const s16x8*)&Bs[r * 32 + lg * 8];
    }
#pragma unroll
    for (int m = 0; m < 4; m++)
#pragma unroll
      for (int n = 0; n < 4; n++)
        acc[m][n] = __builtin_amdgcn_mfma_f32_16x16x32_bf16(af[m], bfr[n], acc[m][n], 0, 0, 0);
    __syncthreads();
  }

#pragma unroll
  for (int m = 0; m < 4; m++)
#pragma unroll
    for (int n = 0; n < 4; n++)
#pragma unroll
      for (int r = 0; r < 4; r++) {
        int row = rowBase + wr * 64 + m * 16 + lg * 4 + r;
        int col = colBase + wc * 64 + n * 16 + lr;
        float v = acc[m][n][r];
        if (EPI == 0) {
          int b = row >> 11, s = row & 2047;
          u16 hv = f2bf(v);
          if (col < 2048) {
            int hh = col >> 7, d = col & 127;
            Oq[(((long)(b * NH + hh)) * SS + s) * HD + d] = hv;
          } else if (col < 2560) {
            int c2 = col - 2048, kh = c2 >> 7, d = c2 & 127;
            Ok[(((long)(b * NKV + kh)) * SS + s) * HD + d] = hv;
          } else {
            int c2 = col - 2560, kh = c2 >> 7, d = c2 & 127;
            Ov[(((long)(b * NKV + kh)) * HD + d) * SS + s] = hv;   // V transposed [d][s]
          }
        } else {
          Of[(long)row * DMODEL + col] = v;
        }
      }
}

// ---------------------------------------------------------------- RoPE in-place on Qr, Kr
__global__ void rope_kernel(u16* __restrict__ Qr, u16* __restrict__ Kr)
{
  long gid = (long)blockIdx.x * 256 + threadIdx.x;
  int i = (int)(gid & 63);
  long row = gid >> 6;
  int s;
  u16* p;
  const long qrows = (long)NB * NH * SS;
  if (row < qrows) { s = (int)(row & 2047); p = Qr + row * HD; }
  else             { long r2 = row - qrows; s = (int)(r2 & 2047); p = Kr + r2 * HD; }
  float inv = exp2f(-(float)i * 0.20762050593046015f);   // log2(10000)/64
  float fr = (float)s * inv;
  float c = cosf(fr), sn = sinf(fr);
  float x1 = bf2f(p[i]), x2 = bf2f(p[i + 64]);
  p[i]      = f2bf(x1 * c + x2 * sn);
  p[i + 64] = f2bf(-x1 * sn + x2 * c);
}

// ---------------------------------------------------------------- flash attention (causal, GQA)
// grid (S/128, NH, NB); 4 waves/block, wave w owns q-rows [qt*128 + w*32, +32).
// K/V tiles staged to LDS via global_load_lds, double-buffered, XOR-swizzled
// (pre-swizzled global src, swizzled ds_read). Per-wave swizzled P buffer.
__global__ __launch_bounds__(256, 2) void attn_fwd(const u16* __restrict__ Qr, const u16* __restrict__ Kr,
                                                   const u16* __restrict__ Vt, u16* __restrict__ Y)
{
  __shared__ __align__(16) u16 Ks[2][64 * 128];   // [kv][d]   16KB each
  __shared__ __align__(16) u16 Vs[2][128 * 64];   // [d][kv]   16KB each
  __shared__ __align__(16) u16 Ps[4][32 * 64];    // per-wave P^T, 4KB each

  const int tid = threadIdx.x, l = tid & 63, w = tid >> 6;
  const int lg = l >> 4, lr = l & 15;
  const int qt = gridDim.x - 1 - blockIdx.x;      // longest blocks first
  const int h = blockIdx.y, b = blockIdx.z;
  const int kvh = h >> 2;
  const int qRow0 = qt * 128 + w * 32;
  const int qMax = qRow0 + 31;
  const int nT = 2 * qt + 2;

  const u16* Qh = Qr + (((long)(b * NH + h)) * SS + qRow0) * HD;
  const u16* Kh = Kr + ((long)(b * NKV + kvh)) * SS * HD;
  const u16* Vh = Vt + ((long)(b * NKV + kvh)) * HD * SS;
  u16* Yh = Y + ((long)b * SS) * DMODEL + h * HD;

  s16x8 qf[2][4];
#pragma unroll
  for (int m = 0; m < 2; m++)
#pragma unroll
    for (int kk = 0; kk < 4; kk++)
      qf[m][kk] = *(const s16x8*)(Qh + (long)(m * 16 + lr) * HD + kk * 32 + lg * 8);

  float mrun[2][4], lrun[2][4];
#pragma unroll
  for (int m = 0; m < 2; m++)
#pragma unroll
    for (int r = 0; r < 4; r++) { mrun[m][r] = -1e30f; lrun[m][r] = 0.f; }
  f32x4 oacc[2][8] = {};
  const float scale = 0.08838834764831845f;       // 1/sqrt(128)
  u16* pp = &Ps[w][0];

  // ---- staging: linear LDS dest, inverse-swizzled global source (m173)
  auto stageK = [&](int buf, int kvb) {
    char* kb = (char*)&Ks[buf][0];
#pragma unroll
    for (int i = 0; i < 4; i++) {
      int L = w * 4096 + i * 1024 + l * 16;       // byte this lane lands at
      int r = L >> 8;                             // kv row 0..63 (256B rows)
      int cl = (L >> 4) & 15;                     // 16B chunk in row
      int cg = (cl & 8) | ((cl ^ r) & 7);
      GLOAD16((const char*)(Kh + (long)(kvb + r) * HD) + cg * 16, kb + w * 4096 + i * 1024);
    }
  };
  auto stageV = [&](int buf, int kvb) {
    char* vb = (char*)&Vs[buf][0];
#pragma unroll
    for (int i = 0; i < 4; i++) {
      int L = w * 4096 + i * 1024 + l * 16;
      int r = L >> 7;                             // d row 0..127 (128B rows)
      int cl = (L >> 4) & 7;
      int cg = (cl ^ r) & 7;
      GLOAD16((const char*)(Vh + (long)r * SS + kvb) + cg * 16, vb + w * 4096 + i * 1024);
    }
  };

  stageK(0, 0); stageV(0, 0);
  __syncthreads();

  for (int t = 0; t < nT; t++) {
    const int cur = t & 1;
    if (t + 1 < nT) { stageK(cur ^ 1, (t + 1) * 64); stageV(cur ^ 1, (t + 1) * 64); }

    if (t * 64 <= qMax) {                          // wave has live rows in this tile
      const char* kb = (const char*)&Ks[cur][0];
      const char* vb = (const char*)&Vs[cur][0];
      // ---- S = Q K^T
      f32x4 sacc[2][4] = {};
#pragma unroll
      for (int kk = 0; kk < 4; kk++) {
        s16x8 kf[4];
#pragma unroll
        for (int n = 0; n < 4; n++) {
          int rr = n * 16 + lr;
          int ch = kk * 4 + lg;
          int chs = (ch & 8) | ((ch ^ rr) & 7);
          kf[n] = *(const s16x8*)(kb + rr * 256 + chs * 16);
        }
#pragma unroll
        for (int m = 0; m < 2; m++)
#pragma unroll
          for (int n = 0; n < 4; n++)
            sacc[m][n] = __builtin_amdgcn_mfma_f32_16x16x32_bf16(qf[m][kk], kf[n], sacc[m][n], 0, 0, 0);
      }
      // ---- scale + mask + row max
      const bool full = (t * 64 + 63 <= qRow0);
      float mx[2][4];
#pragma unroll
      for (int m = 0; m < 2; m++)
#pragma unroll
        for (int r = 0; r < 4; r++) mx[m][r] = -1e30f;
#pragma unroll
      for (int m = 0; m < 2; m++)
#pragma unroll
        for (int n = 0; n < 4; n++) {
          int col = t * 64 + n * 16 + lr;
#pragma unroll
          for (int r = 0; r < 4; r++) {
            int row = qRow0 + m * 16 + lg * 4 + r;
            float v = sacc[m][n][r] * scale;
            if (!full && col > row) v = -1e30f;
            sacc[m][n][r] = v;
            mx[m][r] = fmaxf(mx[m][r], v);
          }
        }
#pragma unroll
      for (int m = 0; m < 2; m++)
#pragma unroll
        for (int r = 0; r < 4; r++) {
          mx[m][r] = fmaxf(mx[m][r], __shfl_xor(mx[m][r], 1));
          mx[m][r] = fmaxf(mx[m][r], __shfl_xor(mx[m][r], 2));
          mx[m][r] = fmaxf(mx[m][r], __shfl_xor(mx[m][r], 4));
          mx[m][r] = fmaxf(mx[m][r], __shfl_xor(mx[m][r], 8));
        }
      float sf[2][4], rs[2][4];
#pragma unroll
      for (int m = 0; m < 2; m++)
#pragma unroll
        for (int r = 0; r < 4; r++) {
          float mnew = fmaxf(mrun[m][r], mx[m][r]);
          sf[m][r] = __expf(mrun[m][r] - mnew);
          mrun[m][r] = mnew;
          rs[m][r] = 0.f;
        }
      // ---- P = exp(S - m), store swizzled P^T, row sums
#pragma unroll
      for (int m = 0; m < 2; m++)
#pragma unroll
        for (int n = 0; n < 4; n++)
#pragma unroll
          for (int r = 0; r < 4; r++) {
            float p = __expf(sacc[m][n][r] - mrun[m][r]);
            rs[m][r] += p;
            int q = m * 16 + lg * 4 + r;
            int byte = (q * 128 + (n * 16 + lr) * 2) ^ ((q & 7) << 4);
            *(u16*)((char*)pp + byte) = f2bf(p);
          }
#pragma unroll
      for (int m = 0; m < 2; m++)
#pragma unroll
        for (int r = 0; r < 4; r++) {
          rs[m][r] += __shfl_xor(rs[m][r], 1);
          rs[m][r] += __shfl_xor(rs[m][r], 2);
          rs[m][r] += __shfl_xor(rs[m][r], 4);
          rs[m][r] += __shfl_xor(rs[m][r], 8);
          lrun[m][r] = lrun[m][r] * sf[m][r] + rs[m][r];
        }
#pragma unroll
      for (int m = 0; m < 2; m++)
#pragma unroll
        for (int n = 0; n < 8; n++)
#pragma unroll
          for (int r = 0; r < 4; r++) oacc[m][n][r] *= sf[m][r];

      asm volatile("s_waitcnt lgkmcnt(0)" ::: "memory");
      __builtin_amdgcn_sched_barrier(0);
      s16x8 pa[2][2];
#pragma unroll
      for (int m = 0; m < 2; m++)
#pragma unroll
        for (int kk = 0; kk < 2; kk++) {
          int q = m * 16 + lr;
          int chs = ((kk * 4 + lg) ^ q) & 7;
          pa[m][kk] = *(const s16x8*)((const char*)pp + q * 128 + chs * 16);
        }
      // ---- O += P V
#pragma unroll
      for (int kk = 0; kk < 2; kk++) {
        s16x8 vf[8];
#pragma unroll
        for (int n = 0; n < 8; n++) {
          int rr = n * 16 + lr;
          int chs = ((kk * 4 + lg) ^ rr) & 7;
          vf[n] = *(const s16x8*)(vb + rr * 128 + chs * 16);
        }
#pragma unroll
        for (int m = 0; m < 2; m++)
#pragma unroll
          for (int n = 0; n < 8; n++)
            oacc[m][n] = __builtin_amdgcn_mfma_f32_16x16x32_bf16(pa[m][kk], vf[n], oacc[m][n], 0, 0, 0);
      }
    }
    __syncthreads();
  }

#pragma unroll
  for (int m = 0; m < 2; m++)
#pragma unroll
    for (int r = 0; r < 4; r++) lrun[m][r] = 1.f / lrun[m][r];
#pragma unroll
  for (int m = 0; m < 2; m++)
#pragma unroll
    for (int n = 0; n < 8; n++)
#pragma unroll
      for (int r = 0; r < 4; r++) {
        float v = oacc[m][n][r] * lrun[m][r];
        Yh[(long)(qRow0 + m * 16 + lg * 4 + r) * DMODEL + n * 16 + lr] = f2bf(v);
      }
}

// ---------------------------------------------------------------- launch
extern "C" void kernel_launch(void* const* d_in, const int* in_sizes, int n_in,
                              void* d_out, int out_size, void* d_ws, size_t ws_size,
                              hipStream_t stream) {
  const float* x  = (const float*)d_in[0];
  const float* wq = (const float*)d_in[1];
  const float* wk = (const float*)d_in[2];
  const float* wv = (const float*)d_in[3];
  const float* wo = (const float*)d_in[4];
  float* out = (float*)d_out;
  char* ws = (char*)d_ws;

  u16* Xb   = (u16*)ws;                    // 33,554,432 B  (aliased as Y after qkv gemm)
  u16* Wqkv = (u16*)(ws + 33554432);       // 12,582,912 B
  u16* Wob  = (u16*)(ws + 46137344);       //  8,388,608 B
  u16* Qr   = (u16*)(ws + 54525952);       // 33,554,432 B
  u16* Kr   = (u16*)(ws + 88080384);       //  8,388,608 B
  u16* Vt   = (u16*)(ws + 96468992);       //  8,388,608 B
  u16* Y    = Xb;

  cast_all<<<26624, 256, 0, stream>>>(x, wq, wk, wv, wo, Xb, Wqkv, Wob);
  gemm_bt<24, 0><<<1536, 256, 0, stream>>>(Xb, Wqkv, DMODEL, Qr, Kr, Vt, nullptr);
  rope_kernel<<<40960, 256, 0, stream>>>(Qr, Kr);
  dim3 ag(SS / 128, NH, NB);
  attn_fwd<<<ag, 256, 0, stream>>>(Qr, Kr, Vt, Y);
  gemm_bt<16, 1><<<1024, 256, 0, stream>>>(Y, Wob, DMODEL, nullptr, nullptr, nullptr, out);
}